// Round 5
// baseline (649.552 us; speedup 1.0000x reference)
//
#include <hip/hip_runtime.h>
#include <hip/hip_bf16.h>

typedef __hip_bfloat16 bf16;
typedef __attribute__((ext_vector_type(8))) short short8;
typedef __attribute__((ext_vector_type(4))) short short4v;
typedef __attribute__((ext_vector_type(4))) float f32x4;

#define DIMC 2048
#define TSEQ 2048
#define NB 2
#define KVH 4
#define NH 16
#define HD 128
#define KVD 512
// softmax scale folded into Wq, in log2 domain: 1/sqrt(128) * log2(e)
#define QSCALE 0.12751744f

__device__ __forceinline__ void mfma16(f32x4& acc, short8 a, short8 b) {
  acc = __builtin_amdgcn_mfma_f32_16x16x32_bf16(a, b, acc, 0, 0, 0);
}

__device__ __forceinline__ void gload_lds16(const bf16* g, bf16* l) {
  __builtin_amdgcn_global_load_lds(
      (const __attribute__((address_space(1))) void*)g,
      (__attribute__((address_space(3))) void*)l, 16, 0, 0);
}

// XOR-swizzle a within-row element index (16B-slot granularity, bf16 elems).
__device__ __forceinline__ int swz(int row, int col) {
  return col ^ ((row & 7) << 3);
}

// ---------------- x: fp32 -> bf16, vectorized ----------------
__global__ __launch_bounds__(256) void f2b(const float* __restrict__ in,
                                           bf16* __restrict__ out, long n4) {
  long i = (long)blockIdx.x * 256 + threadIdx.x;
  if (i >= n4) return;
  const f32x4 v = *(const f32x4*)(in + i * 4);
  union { short4v s; bf16 h[4]; } u;
#pragma unroll
  for (int j = 0; j < 4; ++j) u.h[j] = __float2bfloat16(v[j]);
  *(short4v*)(out + i * 4) = u.s;
}

// ---- transpose weights: fp32 W[2048][C] -> bf16 Wt[C][2048], scaled ----
__global__ __launch_bounds__(256) void transpose_w_f2b(const float* __restrict__ in,
                                                       bf16* __restrict__ out, int C,
                                                       float scale) {
  __shared__ bf16 tile[64][72];
  int rb = blockIdx.y * 64, cb = blockIdx.x * 64;
  int tx = threadIdx.x & 63, ty = threadIdx.x >> 6;
  for (int i = ty; i < 64; i += 4)
    tile[i][tx] = __float2bfloat16(in[(long)(rb + i) * C + cb + tx] * scale);
  __syncthreads();
  for (int i = ty; i < 64; i += 4)
    out[(long)(cb + i) * DIMC + rb + tx] = tile[tx][i];
}

// ---------------- shared GEMM K-loop body (128x128 tile, BK=32) ----------------
#define GEMM_BODY(A_, Bt_, K_)                                                  \
  const int tid = threadIdx.x;                                                  \
  const int lane = tid & 63, wid = tid >> 6;                                    \
  const long m0 = blockIdx.y * 128, n0 = blockIdx.x * 128;                      \
  const int wm = (wid >> 1) * 64, wn = (wid & 1) * 64;                          \
  f32x4 acc[4][4] = {};                                                         \
  const int srow = lane >> 2, scol = (lane & 3) * 8;                            \
  const bf16* Ag = A_ + (m0 + srow) * (long)K_ + scol;                          \
  const bf16* Bg = Bt_ + (n0 + srow) * (long)K_ + scol;                         \
  for (int k0 = 0; k0 < K_; k0 += 32) {                                         \
    for (int p = 0; p < 2; ++p) {                                               \
      int rr = p * 64 + wid * 16;                                               \
      gload_lds16(Ag + (long)rr * K_ + k0, As + rr * 32);                       \
      gload_lds16(Bg + (long)rr * K_ + k0, Bs + rr * 32);                       \
    }                                                                           \
    __syncthreads();                                                            \
    const int ko = (lane >> 4) * 8;                                             \
    short8 af[4], bq[4];                                                        \
    _Pragma("unroll") for (int i = 0; i < 4; ++i) {                             \
      af[i] = *(const short8*)(As + (wm + i * 16 + (lane & 15)) * 32 + ko);     \
      bq[i] = *(const short8*)(Bs + (wn + i * 16 + (lane & 15)) * 32 + ko);     \
    }                                                                           \
    _Pragma("unroll") for (int i = 0; i < 4; ++i)                               \
      _Pragma("unroll") for (int j = 0; j < 4; ++j)                             \
        mfma16(acc[i][j], af[i], bq[j]);                                        \
    __syncthreads();                                                            \
  }                                                                             \
  const int cr = (lane >> 4) * 4, cc = lane & 15;

// ------------- fused QKV GEMM: A[4096][2048] x WT3[3072][2048]^T -------------
// n in [0,2048) -> qp ; [2048,2560) -> kp ; [2560,3072) -> vT scatter.
__global__ __launch_bounds__(256) void gemm_qkv(const bf16* __restrict__ A,
                                                const bf16* __restrict__ Bt,
                                                bf16* __restrict__ qp,
                                                bf16* __restrict__ kp,
                                                bf16* __restrict__ vT) {
  __shared__ bf16 As[128 * 32];
  __shared__ bf16 Bs[128 * 32];
  GEMM_BODY(A, Bt, 2048)
#pragma unroll
  for (int i = 0; i < 4; ++i)
#pragma unroll
    for (int j = 0; j < 4; ++j)
#pragma unroll
      for (int r = 0; r < 4; ++r) {
        long m = m0 + wm + i * 16 + cr + r;
        long n = n0 + wn + j * 16 + cc;
        float val = acc[i][j][r];
        if (n0 < 2048) {
          qp[m * DIMC + n] = __float2bfloat16(val);
        } else if (n0 < 2560) {
          kp[m * KVD + (n - 2048)] = __float2bfloat16(val);
        } else {
          long nn = n - 2560;
          long z = (m >> 11) * 4 + (nn >> 7);
          vT[z * (HD * (long)TSEQ) + (nn & 127) * (long)TSEQ + (m & 2047)] =
              __float2bfloat16(val);
        }
      }
}

// ------------- O GEMM: fp32 output -------------
__global__ __launch_bounds__(256) void gemm_out(const bf16* __restrict__ A,
                                                const bf16* __restrict__ Bt,
                                                float* __restrict__ C) {
  __shared__ bf16 As[128 * 32];
  __shared__ bf16 Bs[128 * 32];
  GEMM_BODY(A, Bt, 2048)
#pragma unroll
  for (int i = 0; i < 4; ++i)
#pragma unroll
    for (int j = 0; j < 4; ++j)
#pragma unroll
      for (int r = 0; r < 4; ++r) {
        long m = m0 + wm + i * 16 + cr + r;
        long n = n0 + wn + j * 16 + cc;
        C[m * DIMC + n] = acc[i][j][r];
      }
}

// ---------------- flash attention fwd, full (non-causal) ----------------
// grid: (T/128, 16 heads, B). 8 waves x 16 q-rows. KV tile 64.
// LDS 48KB -> 3 blocks/CU. XOR-swizzled tiles (no padding). Reg-prefetch.
__global__ __launch_bounds__(512, 6) void attn_fwd(const bf16* __restrict__ Qp,
                                                   const bf16* __restrict__ Kp,
                                                   const bf16* __restrict__ Vt,
                                                   bf16* __restrict__ AO) {
  __shared__ bf16 Ks[64 * 128];    // [s][d], swizzled
  __shared__ bf16 Vts[128 * 64];   // [d][s], swizzled
  __shared__ bf16 Plds[8][16 * 64];// [q][s] per wave, swizzled
  const int tid = threadIdx.x;
  const int lane = tid & 63, wid = tid >> 6;
  const int h = blockIdx.y, b = blockIdx.z;
  const int kv = h >> 2;
  const int t0 = blockIdx.x * 128;
  const int lr = lane & 15, lg = lane >> 4;

  short8 aq[4];
  {
    const bf16* qrow =
        Qp + ((long)(b * TSEQ + t0 + wid * 16 + lr)) * DIMC + h * HD + lg * 8;
#pragma unroll
    for (int c = 0; c < 4; ++c) aq[c] = *(const short8*)(qrow + c * 32);
  }
  f32x4 o[8] = {};
  float mrun[4], lrun[4];
#pragma unroll
  for (int r = 0; r < 4; ++r) { mrun[r] = -1e30f; lrun[r] = 0.f; }

  const bf16* Kg = Kp + (long)b * TSEQ * KVD + kv * HD;
  const bf16* Vg = Vt + ((long)(b * KVH + kv)) * HD * TSEQ;

  // staging ownership: K row tid>>3, 16 elems at (tid&7)*16; V row tid>>2,
  // 16 elems at (tid&3)*16.
  const int krow = tid >> 3, kc0 = (tid & 7) * 16;
  const int vrow = tid >> 2, vc0 = (tid & 3) * 16;
  short8 kreg[2], vreg[2];
#pragma unroll
  for (int p = 0; p < 2; ++p) {
    kreg[p] = *(const short8*)(Kg + (long)krow * KVD + kc0 + p * 8);
    vreg[p] = *(const short8*)(Vg + (long)vrow * TSEQ + vc0 + p * 8);
  }

  for (int s0 = 0; s0 < TSEQ; s0 += 64) {
    __syncthreads();  // prev-tile LDS reads done
#pragma unroll
    for (int p = 0; p < 2; ++p) {
      *(short8*)(Ks + krow * 128 + swz(krow, kc0 + p * 8)) = kreg[p];
      *(short8*)(Vts + vrow * 64 + swz(vrow, vc0 + p * 8)) = vreg[p];
    }
    __syncthreads();
    if (s0 + 64 < TSEQ) {  // prefetch next tile; completes under compute
#pragma unroll
      for (int p = 0; p < 2; ++p) {
        kreg[p] = *(const short8*)(Kg + (long)(s0 + 64 + krow) * KVD + kc0 + p * 8);
        vreg[p] = *(const short8*)(Vg + (long)vrow * TSEQ + s0 + 64 + vc0 + p * 8);
      }
    }

    // S = Q K^T (log2-scaled; scale folded into Wq)
    f32x4 sacc[4] = {};
#pragma unroll
    for (int sf = 0; sf < 4; ++sf)
#pragma unroll
      for (int c = 0; c < 4; ++c) {
        int row = sf * 16 + lr;
        short8 kf = *(const short8*)(Ks + row * 128 + swz(row, c * 32 + lg * 8));
        mfma16(sacc[sf], aq[c], kf);
      }

    // online softmax (base-2); lane holds rows lg*4+r, col sf*16+lr
    float tmax[4];
#pragma unroll
    for (int r = 0; r < 4; ++r)
      tmax[r] = fmaxf(fmaxf(sacc[0][r], sacc[1][r]),
                      fmaxf(sacc[2][r], sacc[3][r]));
#pragma unroll
    for (int r = 0; r < 4; ++r)
#pragma unroll
      for (int mm = 1; mm < 16; mm <<= 1)
        tmax[r] = fmaxf(tmax[r], __shfl_xor(tmax[r], mm));
    int need = 0;
#pragma unroll
    for (int r = 0; r < 4; ++r) need |= (tmax[r] > mrun[r]);
    if (__any(need)) {  // defer-max: skip rescale when max didn't grow
#pragma unroll
      for (int r = 0; r < 4; ++r) {
        float mnew = fmaxf(mrun[r], tmax[r]);
        float fac = exp2f(mrun[r] - mnew);
        mrun[r] = mnew;
        lrun[r] *= fac;
#pragma unroll
        for (int df = 0; df < 8; ++df) o[df][r] *= fac;
      }
    }
    float psum[4] = {0.f, 0.f, 0.f, 0.f};
    bf16* Pw = Plds[wid];
#pragma unroll
    for (int sf = 0; sf < 4; ++sf)
#pragma unroll
      for (int r = 0; r < 4; ++r) {
        float p = exp2f(sacc[sf][r] - mrun[r]);
        psum[r] += p;
        int prow = lg * 4 + r;
        Pw[prow * 64 + swz(prow, sf * 16 + lr)] = __float2bfloat16(p);
      }
#pragma unroll
    for (int r = 0; r < 4; ++r) {
#pragma unroll
      for (int mm = 1; mm < 16; mm <<= 1)
        psum[r] += __shfl_xor(psum[r], mm);
      lrun[r] += psum[r];
    }

    // O += P V
#pragma unroll
    for (int c2 = 0; c2 < 2; ++c2) {
      short8 pa = *(const short8*)(Pw + lr * 64 + swz(lr, c2 * 32 + lg * 8));
#pragma unroll
      for (int df = 0; df < 8; ++df) {
        int vr = df * 16 + lr;
        short8 vf = *(const short8*)(Vts + vr * 64 + swz(vr, c2 * 32 + lg * 8));
        mfma16(o[df], pa, vf);
      }
    }
  }

  bf16* orow =
      AO + ((long)(b * TSEQ + t0 + wid * 16 + lg * 4)) * DIMC + h * HD + lr;
#pragma unroll
  for (int df = 0; df < 8; ++df)
#pragma unroll
    for (int r = 0; r < 4; ++r) {
      float v = o[df][r] / lrun[r];
      orow[(long)r * DIMC + df * 16] = __float2bfloat16(v);
    }
}

extern "C" void kernel_launch(void* const* d_in, const int* in_sizes, int n_in,
                              void* d_out, int out_size, void* d_ws, size_t ws_size,
                              hipStream_t stream) {
  const float* x  = (const float*)d_in[0];
  const float* Wq = (const float*)d_in[1];
  const float* Wk = (const float*)d_in[2];
  const float* Wv = (const float*)d_in[3];
  const float* Wo = (const float*)d_in[4];
  float* out = (float*)d_out;
  bf16* ws = (bf16*)d_ws;

  bf16* xb  = ws;                 // [4096][2048] x (bf16); later reused as ao
  bf16* WT3 = xb + 8388608;       // [3072][2048] WqT|WkT|WvT, then WoT (reuse)
  bf16* qp  = WT3 + 6291456;      // [4096][2048]
  bf16* kp  = qp + 8388608;       // [4096][512]
  bf16* vT  = kp + 2097152;       // [8][128][2048]
  // total 27.3M bf16 = 54.6 MB

  f2b<<<8192, 256, 0, stream>>>(x, xb, 2097152);
  transpose_w_f2b<<<dim3(32, 32), 256, 0, stream>>>(Wq, WT3, 2048, QSCALE);
  transpose_w_f2b<<<dim3(8, 32), 256, 0, stream>>>(Wk, WT3 + (long)2048 * 2048, 512, 1.0f);
  transpose_w_f2b<<<dim3(8, 32), 256, 0, stream>>>(Wv, WT3 + (long)2560 * 2048, 512, 1.0f);

  gemm_qkv<<<dim3(24, 32), 256, 0, stream>>>(xb, WT3, qp, kp, vT);

  transpose_w_f2b<<<dim3(32, 32), 256, 0, stream>>>(Wo, WT3, 2048, 1.0f);  // reuse

  bf16* ao = xb;  // x dead after QKV gemm
  attn_fwd<<<dim3(16, 16, 2), 512, 0, stream>>>(qp, kp, vT, ao);

  gemm_out<<<dim3(16, 32), 256, 0, stream>>>(ao, WT3, out);
}

// Round 6
// 300.231 us; speedup vs baseline: 2.1635x; 2.1635x over previous
//
#include <hip/hip_runtime.h>
#include <hip/hip_bf16.h>

typedef __hip_bfloat16 bf16;
typedef __attribute__((ext_vector_type(8))) short short8;
typedef __attribute__((ext_vector_type(4))) short short4v;
typedef __attribute__((ext_vector_type(4))) float f32x4;

#define DIMC 2048
#define TSEQ 2048
#define NB 2
#define KVH 4
#define NH 16
#define HD 128
#define KVD 512
// softmax scale folded into Wq, in log2 domain: 1/sqrt(128) * log2(e)
#define QSCALE 0.12751744f

__device__ __forceinline__ void mfma16(f32x4& acc, short8 a, short8 b) {
  acc = __builtin_amdgcn_mfma_f32_16x16x32_bf16(a, b, acc, 0, 0, 0);
}

__device__ __forceinline__ void gload_lds16(const bf16* g, bf16* l) {
  __builtin_amdgcn_global_load_lds(
      (const __attribute__((address_space(1))) void*)g,
      (__attribute__((address_space(3))) void*)l, 16, 0, 0);
}

// XOR-swizzle a within-row element index (16B-slot granularity, bf16 elems).
__device__ __forceinline__ int swz(int row, int col) {
  return col ^ ((row & 7) << 3);
}

// ---------------- x: fp32 -> bf16, vectorized ----------------
__global__ __launch_bounds__(256) void f2b(const float* __restrict__ in,
                                           bf16* __restrict__ out, long n4) {
  long i = (long)blockIdx.x * 256 + threadIdx.x;
  if (i >= n4) return;
  const f32x4 v = *(const f32x4*)(in + i * 4);
  union { short4v s; bf16 h[4]; } u;
#pragma unroll
  for (int j = 0; j < 4; ++j) u.h[j] = __float2bfloat16(v[j]);
  *(short4v*)(out + i * 4) = u.s;
}

// ---- transpose weights: fp32 W[2048][C] -> bf16 Wt[C][2048], scaled ----
__global__ __launch_bounds__(256) void transpose_w_f2b(const float* __restrict__ in,
                                                       bf16* __restrict__ out, int C,
                                                       float scale) {
  __shared__ bf16 tile[64][72];
  int rb = blockIdx.y * 64, cb = blockIdx.x * 64;
  int tx = threadIdx.x & 63, ty = threadIdx.x >> 6;
  for (int i = ty; i < 64; i += 4)
    tile[i][tx] = __float2bfloat16(in[(long)(rb + i) * C + cb + tx] * scale);
  __syncthreads();
  for (int i = ty; i < 64; i += 4)
    out[(long)(cb + i) * DIMC + rb + tx] = tile[tx][i];
}

// ---------------- shared GEMM K-loop body (128x128 tile, BK=32) ----------------
#define GEMM_BODY(A_, Bt_, K_)                                                  \
  const int tid = threadIdx.x;                                                  \
  const int lane = tid & 63, wid = tid >> 6;                                    \
  const long m0 = blockIdx.y * 128, n0 = blockIdx.x * 128;                      \
  const int wm = (wid >> 1) * 64, wn = (wid & 1) * 64;                          \
  f32x4 acc[4][4] = {};                                                         \
  const int srow = lane >> 2, scol = (lane & 3) * 8;                            \
  const bf16* Ag = A_ + (m0 + srow) * (long)K_ + scol;                          \
  const bf16* Bg = Bt_ + (n0 + srow) * (long)K_ + scol;                         \
  for (int k0 = 0; k0 < K_; k0 += 32) {                                         \
    for (int p = 0; p < 2; ++p) {                                               \
      int rr = p * 64 + wid * 16;                                               \
      gload_lds16(Ag + (long)rr * K_ + k0, As + rr * 32);                       \
      gload_lds16(Bg + (long)rr * K_ + k0, Bs + rr * 32);                       \
    }                                                                           \
    __syncthreads();                                                            \
    const int ko = (lane >> 4) * 8;                                             \
    short8 af[4], bq[4];                                                        \
    _Pragma("unroll") for (int i = 0; i < 4; ++i) {                             \
      af[i] = *(const short8*)(As + (wm + i * 16 + (lane & 15)) * 32 + ko);     \
      bq[i] = *(const short8*)(Bs + (wn + i * 16 + (lane & 15)) * 32 + ko);     \
    }                                                                           \
    _Pragma("unroll") for (int i = 0; i < 4; ++i)                               \
      _Pragma("unroll") for (int j = 0; j < 4; ++j)                             \
        mfma16(acc[i][j], af[i], bq[j]);                                        \
    __syncthreads();                                                            \
  }                                                                             \
  const int cr = (lane >> 4) * 4, cc = lane & 15;

// ------------- fused QKV GEMM: A[4096][2048] x WT3[3072][2048]^T -------------
// n in [0,2048) -> qp ; [2048,2560) -> kp ; [2560,3072) -> vT scatter.
__global__ __launch_bounds__(256) void gemm_qkv(const bf16* __restrict__ A,
                                                const bf16* __restrict__ Bt,
                                                bf16* __restrict__ qp,
                                                bf16* __restrict__ kp,
                                                bf16* __restrict__ vT) {
  __shared__ bf16 As[128 * 32];
  __shared__ bf16 Bs[128 * 32];
  GEMM_BODY(A, Bt, 2048)
#pragma unroll
  for (int i = 0; i < 4; ++i)
#pragma unroll
    for (int j = 0; j < 4; ++j)
#pragma unroll
      for (int r = 0; r < 4; ++r) {
        long m = m0 + wm + i * 16 + cr + r;
        long n = n0 + wn + j * 16 + cc;
        float val = acc[i][j][r];
        if (n0 < 2048) {
          qp[m * DIMC + n] = __float2bfloat16(val);
        } else if (n0 < 2560) {
          kp[m * KVD + (n - 2048)] = __float2bfloat16(val);
        } else {
          long nn = n - 2560;
          long z = (m >> 11) * 4 + (nn >> 7);
          vT[z * (HD * (long)TSEQ) + (nn & 127) * (long)TSEQ + (m & 2047)] =
              __float2bfloat16(val);
        }
      }
}

// ------------- O GEMM: fp32 output -------------
__global__ __launch_bounds__(256) void gemm_out(const bf16* __restrict__ A,
                                                const bf16* __restrict__ Bt,
                                                float* __restrict__ C) {
  __shared__ bf16 As[128 * 32];
  __shared__ bf16 Bs[128 * 32];
  GEMM_BODY(A, Bt, 2048)
#pragma unroll
  for (int i = 0; i < 4; ++i)
#pragma unroll
    for (int j = 0; j < 4; ++j)
#pragma unroll
      for (int r = 0; r < 4; ++r) {
        long m = m0 + wm + i * 16 + cr + r;
        long n = n0 + wn + j * 16 + cc;
        C[m * DIMC + n] = acc[i][j][r];
      }
}

// ---------------- flash attention fwd, full (non-causal) ----------------
// grid: (T/128, 16 heads, B). 8 waves x 16 q-rows. KV tile 64.
// LDS 48KB; XOR-swizzled tiles (no padding). Reg-prefetch next tile.
// launch_bounds (512,4): (512,6) capped VGPR at 40 -> 1GB/dispatch spill
// traffic (R5 post-mortem). VGPR=60 fits 24 waves/CU by itself.
__global__ __launch_bounds__(512, 4) void attn_fwd(const bf16* __restrict__ Qp,
                                                   const bf16* __restrict__ Kp,
                                                   const bf16* __restrict__ Vt,
                                                   bf16* __restrict__ AO) {
  __shared__ bf16 Ks[64 * 128];    // [s][d], swizzled
  __shared__ bf16 Vts[128 * 64];   // [d][s], swizzled
  __shared__ bf16 Plds[8][16 * 64];// [q][s] per wave, swizzled
  const int tid = threadIdx.x;
  const int lane = tid & 63, wid = tid >> 6;
  const int h = blockIdx.y, b = blockIdx.z;
  const int kv = h >> 2;
  const int t0 = blockIdx.x * 128;
  const int lr = lane & 15, lg = lane >> 4;

  short8 aq[4];
  {
    const bf16* qrow =
        Qp + ((long)(b * TSEQ + t0 + wid * 16 + lr)) * DIMC + h * HD + lg * 8;
#pragma unroll
    for (int c = 0; c < 4; ++c) aq[c] = *(const short8*)(qrow + c * 32);
  }
  f32x4 o[8] = {};
  float mrun[4], lrun[4];
#pragma unroll
  for (int r = 0; r < 4; ++r) { mrun[r] = -1e30f; lrun[r] = 0.f; }

  const bf16* Kg = Kp + (long)b * TSEQ * KVD + kv * HD;
  const bf16* Vg = Vt + ((long)(b * KVH + kv)) * HD * TSEQ;

  // staging ownership: K row tid>>3, 16 elems at (tid&7)*16; V row tid>>2,
  // 16 elems at (tid&3)*16.
  const int krow = tid >> 3, kc0 = (tid & 7) * 16;
  const int vrow = tid >> 2, vc0 = (tid & 3) * 16;
  short8 kreg[2], vreg[2];
#pragma unroll
  for (int p = 0; p < 2; ++p) {
    kreg[p] = *(const short8*)(Kg + (long)krow * KVD + kc0 + p * 8);
    vreg[p] = *(const short8*)(Vg + (long)vrow * TSEQ + vc0 + p * 8);
  }

  for (int s0 = 0; s0 < TSEQ; s0 += 64) {
    __syncthreads();  // prev-tile LDS reads done
#pragma unroll
    for (int p = 0; p < 2; ++p) {
      *(short8*)(Ks + krow * 128 + swz(krow, kc0 + p * 8)) = kreg[p];
      *(short8*)(Vts + vrow * 64 + swz(vrow, vc0 + p * 8)) = vreg[p];
    }
    __syncthreads();
    if (s0 + 64 < TSEQ) {  // prefetch next tile; completes under compute
#pragma unroll
      for (int p = 0; p < 2; ++p) {
        kreg[p] = *(const short8*)(Kg + (long)(s0 + 64 + krow) * KVD + kc0 + p * 8);
        vreg[p] = *(const short8*)(Vg + (long)vrow * TSEQ + s0 + 64 + vc0 + p * 8);
      }
    }

    // S = Q K^T (log2-scaled; scale folded into Wq)
    f32x4 sacc[4] = {};
#pragma unroll
    for (int sf = 0; sf < 4; ++sf)
#pragma unroll
      for (int c = 0; c < 4; ++c) {
        int row = sf * 16 + lr;
        short8 kf = *(const short8*)(Ks + row * 128 + swz(row, c * 32 + lg * 8));
        mfma16(sacc[sf], aq[c], kf);
      }

    // online softmax (base-2); lane holds rows lg*4+r, col sf*16+lr
    float tmax[4];
#pragma unroll
    for (int r = 0; r < 4; ++r)
      tmax[r] = fmaxf(fmaxf(sacc[0][r], sacc[1][r]),
                      fmaxf(sacc[2][r], sacc[3][r]));
#pragma unroll
    for (int r = 0; r < 4; ++r)
#pragma unroll
      for (int mm = 1; mm < 16; mm <<= 1)
        tmax[r] = fmaxf(tmax[r], __shfl_xor(tmax[r], mm));
    int need = 0;
#pragma unroll
    for (int r = 0; r < 4; ++r) need |= (tmax[r] > mrun[r]);
    if (__any(need)) {  // defer-max: skip rescale when max didn't grow
#pragma unroll
      for (int r = 0; r < 4; ++r) {
        float mnew = fmaxf(mrun[r], tmax[r]);
        float fac = exp2f(mrun[r] - mnew);
        mrun[r] = mnew;
        lrun[r] *= fac;
#pragma unroll
        for (int df = 0; df < 8; ++df) o[df][r] *= fac;
      }
    }
    float psum[4] = {0.f, 0.f, 0.f, 0.f};
    bf16* Pw = Plds[wid];
#pragma unroll
    for (int sf = 0; sf < 4; ++sf)
#pragma unroll
      for (int r = 0; r < 4; ++r) {
        float p = exp2f(sacc[sf][r] - mrun[r]);
        psum[r] += p;
        int prow = lg * 4 + r;
        Pw[prow * 64 + swz(prow, sf * 16 + lr)] = __float2bfloat16(p);
      }
#pragma unroll
    for (int r = 0; r < 4; ++r) {
#pragma unroll
      for (int mm = 1; mm < 16; mm <<= 1)
        psum[r] += __shfl_xor(psum[r], mm);
      lrun[r] += psum[r];
    }

    // O += P V
#pragma unroll
    for (int c2 = 0; c2 < 2; ++c2) {
      short8 pa = *(const short8*)(Pw + lr * 64 + swz(lr, c2 * 32 + lg * 8));
#pragma unroll
      for (int df = 0; df < 8; ++df) {
        int vr = df * 16 + lr;
        short8 vf = *(const short8*)(Vts + vr * 64 + swz(vr, c2 * 32 + lg * 8));
        mfma16(o[df], pa, vf);
      }
    }
  }

  bf16* orow =
      AO + ((long)(b * TSEQ + t0 + wid * 16 + lg * 4)) * DIMC + h * HD + lr;
#pragma unroll
  for (int df = 0; df < 8; ++df)
#pragma unroll
    for (int r = 0; r < 4; ++r) {
      float v = o[df][r] / lrun[r];
      orow[(long)r * DIMC + df * 16] = __float2bfloat16(v);
    }
}

extern "C" void kernel_launch(void* const* d_in, const int* in_sizes, int n_in,
                              void* d_out, int out_size, void* d_ws, size_t ws_size,
                              hipStream_t stream) {
  const float* x  = (const float*)d_in[0];
  const float* Wq = (const float*)d_in[1];
  const float* Wk = (const float*)d_in[2];
  const float* Wv = (const float*)d_in[3];
  const float* Wo = (const float*)d_in[4];
  float* out = (float*)d_out;
  bf16* ws = (bf16*)d_ws;

  bf16* xb  = ws;                 // [4096][2048] x (bf16); later reused as ao
  bf16* WT3 = xb + 8388608;       // [3072][2048] WqT|WkT|WvT, then WoT (reuse)
  bf16* qp  = WT3 + 6291456;      // [4096][2048]
  bf16* kp  = qp + 8388608;       // [4096][512]
  bf16* vT  = kp + 2097152;       // [8][128][2048]
  // total 27.3M bf16 = 54.6 MB

  f2b<<<8192, 256, 0, stream>>>(x, xb, 2097152);
  transpose_w_f2b<<<dim3(32, 32), 256, 0, stream>>>(Wq, WT3, 2048, QSCALE);
  transpose_w_f2b<<<dim3(8, 32), 256, 0, stream>>>(Wk, WT3 + (long)2048 * 2048, 512, 1.0f);
  transpose_w_f2b<<<dim3(8, 32), 256, 0, stream>>>(Wv, WT3 + (long)2560 * 2048, 512, 1.0f);

  gemm_qkv<<<dim3(24, 32), 256, 0, stream>>>(xb, WT3, qp, kp, vT);

  transpose_w_f2b<<<dim3(32, 32), 256, 0, stream>>>(Wo, WT3, 2048, 1.0f);  // reuse

  bf16* ao = xb;  // x dead after QKV gemm
  attn_fwd<<<dim3(16, 16, 2), 512, 0, stream>>>(qp, kp, vT, ao);

  gemm_out<<<dim3(16, 32), 256, 0, stream>>>(ao, WT3, out);
}

// Round 7
// 271.326 us; speedup vs baseline: 2.3940x; 1.1065x over previous
//
#include <hip/hip_runtime.h>
#include <hip/hip_bf16.h>

typedef __hip_bfloat16 bf16;
typedef __attribute__((ext_vector_type(8))) short short8;
typedef __attribute__((ext_vector_type(4))) short short4v;
typedef __attribute__((ext_vector_type(4))) float f32x4;

#define DIMC 2048
#define TSEQ 2048
#define NB 2
#define KVH 4
#define NH 16
#define HD 128
#define KVD 512
// softmax scale folded into Wq, in log2 domain: 1/sqrt(128) * log2(e)
#define QSCALE 0.12751744f

__device__ __forceinline__ void mfma16(f32x4& acc, short8 a, short8 b) {
  acc = __builtin_amdgcn_mfma_f32_16x16x32_bf16(a, b, acc, 0, 0, 0);
}

__device__ __forceinline__ void gload_lds16(const bf16* g, bf16* l) {
  __builtin_amdgcn_global_load_lds(
      (const __attribute__((address_space(1))) void*)g,
      (__attribute__((address_space(3))) void*)l, 16, 0, 0);
}

// XOR-swizzle a within-row element index (16B-slot granularity, bf16 elems).
__device__ __forceinline__ int swz(int row, int col) {
  return col ^ ((row & 7) << 3);
}

// ---------------- x: fp32 -> bf16, vectorized ----------------
__global__ __launch_bounds__(256) void f2b(const float* __restrict__ in,
                                           bf16* __restrict__ out, long n4) {
  long i = (long)blockIdx.x * 256 + threadIdx.x;
  if (i >= n4) return;
  const f32x4 v = *(const f32x4*)(in + i * 4);
  union { short4v s; bf16 h[4]; } u;
#pragma unroll
  for (int j = 0; j < 4; ++j) u.h[j] = __float2bfloat16(v[j]);
  *(short4v*)(out + i * 4) = u.s;
}

// ---- transpose weights: fp32 W[2048][C] -> bf16 Wt[C][2048], scaled ----
__global__ __launch_bounds__(256) void transpose_w_f2b(const float* __restrict__ in,
                                                       bf16* __restrict__ out, int C,
                                                       float scale) {
  __shared__ bf16 tile[64][72];
  int rb = blockIdx.y * 64, cb = blockIdx.x * 64;
  int tx = threadIdx.x & 63, ty = threadIdx.x >> 6;
  for (int i = ty; i < 64; i += 4)
    tile[i][tx] = __float2bfloat16(in[(long)(rb + i) * C + cb + tx] * scale);
  __syncthreads();
  for (int i = ty; i < 64; i += 4)
    out[(long)(cb + i) * DIMC + rb + tx] = tile[tx][i];
}

// ---------------- shared GEMM K-loop body (128x128 tile, BK=32) ----------------
#define GEMM_BODY(A_, Bt_, K_)                                                  \
  const int tid = threadIdx.x;                                                  \
  const int lane = tid & 63, wid = tid >> 6;                                    \
  const long m0 = blockIdx.y * 128, n0 = blockIdx.x * 128;                      \
  const int wm = (wid >> 1) * 64, wn = (wid & 1) * 64;                          \
  f32x4 acc[4][4] = {};                                                         \
  const int srow = lane >> 2, scol = (lane & 3) * 8;                            \
  const bf16* Ag = A_ + (m0 + srow) * (long)K_ + scol;                          \
  const bf16* Bg = Bt_ + (n0 + srow) * (long)K_ + scol;                         \
  for (int k0 = 0; k0 < K_; k0 += 32) {                                         \
    for (int p = 0; p < 2; ++p) {                                               \
      int rr = p * 64 + wid * 16;                                               \
      gload_lds16(Ag + (long)rr * K_ + k0, As + rr * 32);                       \
      gload_lds16(Bg + (long)rr * K_ + k0, Bs + rr * 32);                       \
    }                                                                           \
    __syncthreads();                                                            \
    const int ko = (lane >> 4) * 8;                                             \
    short8 af[4], bq[4];                                                        \
    _Pragma("unroll") for (int i = 0; i < 4; ++i) {                             \
      af[i] = *(const short8*)(As + (wm + i * 16 + (lane & 15)) * 32 + ko);     \
      bq[i] = *(const short8*)(Bs + (wn + i * 16 + (lane & 15)) * 32 + ko);     \
    }                                                                           \
    _Pragma("unroll") for (int i = 0; i < 4; ++i)                               \
      _Pragma("unroll") for (int j = 0; j < 4; ++j)                             \
        mfma16(acc[i][j], af[i], bq[j]);                                        \
    __syncthreads();                                                            \
  }                                                                             \
  const int cr = (lane >> 4) * 4, cc = lane & 15;

// ------------- fused QKV GEMM: A[4096][2048] x WT3[3072][2048]^T -------------
// n in [0,2048) -> qp ; [2048,2560) -> kp ; [2560,3072) -> vT scatter.
__global__ __launch_bounds__(256) void gemm_qkv(const bf16* __restrict__ A,
                                                const bf16* __restrict__ Bt,
                                                bf16* __restrict__ qp,
                                                bf16* __restrict__ kp,
                                                bf16* __restrict__ vT) {
  __shared__ bf16 As[128 * 32];
  __shared__ bf16 Bs[128 * 32];
  GEMM_BODY(A, Bt, 2048)
#pragma unroll
  for (int i = 0; i < 4; ++i)
#pragma unroll
    for (int j = 0; j < 4; ++j)
#pragma unroll
      for (int r = 0; r < 4; ++r) {
        long m = m0 + wm + i * 16 + cr + r;
        long n = n0 + wn + j * 16 + cc;
        float val = acc[i][j][r];
        if (n0 < 2048) {
          qp[m * DIMC + n] = __float2bfloat16(val);
        } else if (n0 < 2560) {
          kp[m * KVD + (n - 2048)] = __float2bfloat16(val);
        } else {
          long nn = n - 2560;
          long z = (m >> 11) * 4 + (nn >> 7);
          vT[z * (HD * (long)TSEQ) + (nn & 127) * (long)TSEQ + (m & 2047)] =
              __float2bfloat16(val);
        }
      }
}

// ------------- O GEMM: fp32 output -------------
__global__ __launch_bounds__(256) void gemm_out(const bf16* __restrict__ A,
                                                const bf16* __restrict__ Bt,
                                                float* __restrict__ C) {
  __shared__ bf16 As[128 * 32];
  __shared__ bf16 Bs[128 * 32];
  GEMM_BODY(A, Bt, 2048)
#pragma unroll
  for (int i = 0; i < 4; ++i)
#pragma unroll
    for (int j = 0; j < 4; ++j)
#pragma unroll
      for (int r = 0; r < 4; ++r) {
        long m = m0 + wm + i * 16 + cr + r;
        long n = n0 + wn + j * 16 + cc;
        C[m * DIMC + n] = acc[i][j][r];
      }
}

// ---------------- flash attention fwd, full (non-causal) ----------------
// Swapped-operand structure (m214-style): QK^T computed as mfma(K,Q) so each
// lane owns ONE q-row (q=lane&15) and 16 s-values -> scalar mrun/lrun, 2-step
// shuffle reductions, P kept entirely in registers (k-permutation freedom:
// A and B frags share the same k-bijection). PV = mfma(V^T, P) -> O^T.
// V LDS uses additive slot rotation (phys_slot = (slot+row)&7): write is
// exactly 8 lanes per 4-bank group (conflict-free); XOR can't do this (coset).
__global__ __launch_bounds__(512, 4) void attn_fwd(const bf16* __restrict__ Qp,
                                                   const bf16* __restrict__ Kp,
                                                   const bf16* __restrict__ Vt,
                                                   bf16* __restrict__ AO) {
  __shared__ bf16 Ks[64 * 128];    // [s][d], XOR-swizzled
  __shared__ bf16 Vts[128 * 64];   // [d][s], slot-rotated
  const int tid = threadIdx.x;
  const int lane = tid & 63, wid = tid >> 6;
  const int h = blockIdx.y, b = blockIdx.z;
  const int kv = h >> 2;
  const int t0 = blockIdx.x * 128;
  const int lr = lane & 15, lg = lane >> 4;

  short8 aq[4];
  {
    const bf16* qrow =
        Qp + ((long)(b * TSEQ + t0 + wid * 16 + lr)) * DIMC + h * HD + lg * 8;
#pragma unroll
    for (int c = 0; c < 4; ++c) aq[c] = *(const short8*)(qrow + c * 32);
  }
  f32x4 o[8] = {};
  float mrun = -1e30f, lrun = 0.f;

  const bf16* Kg = Kp + (long)b * TSEQ * KVD + kv * HD;
  const bf16* Vg = Vt + ((long)(b * KVH + kv)) * HD * TSEQ;

  // staging ownership: K row tid>>3, 16 elems at (tid&7)*16;
  // V row tid>>2, logical slots (tid&3) and (tid&3)+4 (8 elems each).
  const int krow = tid >> 3, kc0 = (tid & 7) * 16;
  const int vrow = tid >> 2, va = tid & 3;
  short8 kreg[2], vreg[2];
#pragma unroll
  for (int p = 0; p < 2; ++p) {
    kreg[p] = *(const short8*)(Kg + (long)krow * KVD + kc0 + p * 8);
    vreg[p] = *(const short8*)(Vg + (long)vrow * TSEQ + (va + 4 * p) * 8);
  }

  for (int s0 = 0; s0 < TSEQ; s0 += 64) {
    __syncthreads();  // prev-tile LDS reads done
#pragma unroll
    for (int p = 0; p < 2; ++p) {
      *(short8*)(Ks + krow * 128 + swz(krow, kc0 + p * 8)) = kreg[p];
      *(short8*)(Vts + vrow * 64 + ((va + 4 * p + vrow) & 7) * 8) = vreg[p];
    }
    __syncthreads();
    if (s0 + 64 < TSEQ) {  // prefetch next tile; completes under compute
#pragma unroll
      for (int p = 0; p < 2; ++p) {
        kreg[p] = *(const short8*)(Kg + (long)(s0 + 64 + krow) * KVD + kc0 + p * 8);
        vreg[p] = *(const short8*)(Vg + (long)vrow * TSEQ + s0 + 64 + (va + 4 * p) * 8);
      }
    }

    // S^T = K Q^T : lane holds q=lr, s = sf*16 + lg*4 + r
    f32x4 sacc[4] = {};
#pragma unroll
    for (int sf = 0; sf < 4; ++sf)
#pragma unroll
      for (int c = 0; c < 4; ++c) {
        int row = sf * 16 + lr;
        short8 kf = *(const short8*)(Ks + row * 128 + swz(row, c * 32 + lg * 8));
        mfma16(sacc[sf], kf, aq[c]);  // swapped operands
      }

    // online softmax (base-2), per-lane scalar state
    float tmax = sacc[0][0];
#pragma unroll
    for (int sf = 0; sf < 4; ++sf)
#pragma unroll
      for (int r = 0; r < 4; ++r) tmax = fmaxf(tmax, sacc[sf][r]);
    tmax = fmaxf(tmax, __shfl_xor(tmax, 16));
    tmax = fmaxf(tmax, __shfl_xor(tmax, 32));
    if (__any(tmax > mrun)) {  // defer-max
      float mnew = fmaxf(mrun, tmax);
      float fac = exp2f(mrun - mnew);
      mrun = mnew;
      lrun *= fac;
#pragma unroll
      for (int df = 0; df < 8; ++df) o[df] *= fac;
    }
    float p4[4][4];
    float ps = 0.f;
#pragma unroll
    for (int sf = 0; sf < 4; ++sf)
#pragma unroll
      for (int r = 0; r < 4; ++r) {
        float pv = exp2f(sacc[sf][r] - mrun);
        p4[sf][r] = pv;
        ps += pv;
      }
    ps += __shfl_xor(ps, 16);
    ps += __shfl_xor(ps, 32);
    lrun += ps;

    // pack P to bf16 B-frags (k-order: s = (2c2+(j>>2))*16 + lg*4 + (j&3))
    union { short8 s; bf16 h[8]; } pb[2];
#pragma unroll
    for (int c2 = 0; c2 < 2; ++c2)
#pragma unroll
      for (int r = 0; r < 4; ++r) {
        pb[c2].h[r] = __float2bfloat16(p4[2 * c2][r]);
        pb[c2].h[4 + r] = __float2bfloat16(p4[2 * c2 + 1][r]);
      }

    // O^T += V^T P : A-frag from Vts rows d=df*16+lr, k-order matching pb
#pragma unroll
    for (int c2 = 0; c2 < 2; ++c2) {
      const int l0 = 4 * c2 + (lg >> 1), w0 = (lg & 1) * 4;
#pragma unroll
      for (int df = 0; df < 8; ++df) {
        int row = df * 16 + lr;
        union { short8 s; short4v q[2]; } vf;
        vf.q[0] = *(const short4v*)(Vts + row * 64 + ((l0 + row) & 7) * 8 + w0);
        vf.q[1] = *(const short4v*)(Vts + row * 64 + ((l0 + 2 + row) & 7) * 8 + w0);
        mfma16(o[df], vf.s, pb[c2].s);
      }
    }
  }

  // lane holds O^T[d = df*16 + lg*4 + r][q = lr]
  float inv = 1.0f / lrun;
  bf16* obase =
      AO + ((long)(b * TSEQ + t0 + wid * 16 + lr)) * DIMC + h * HD + lg * 4;
#pragma unroll
  for (int df = 0; df < 8; ++df) {
    union { short4v s; bf16 h[4]; } ov;
#pragma unroll
    for (int r = 0; r < 4; ++r) ov.h[r] = __float2bfloat16(o[df][r] * inv);
    *(short4v*)(obase + df * 16) = ov.s;
  }
}

extern "C" void kernel_launch(void* const* d_in, const int* in_sizes, int n_in,
                              void* d_out, int out_size, void* d_ws, size_t ws_size,
                              hipStream_t stream) {
  const float* x  = (const float*)d_in[0];
  const float* Wq = (const float*)d_in[1];
  const float* Wk = (const float*)d_in[2];
  const float* Wv = (const float*)d_in[3];
  const float* Wo = (const float*)d_in[4];
  float* out = (float*)d_out;
  bf16* ws = (bf16*)d_ws;

  bf16* xb  = ws;                 // [4096][2048] x (bf16); later reused as ao
  bf16* WT3 = xb + 8388608;       // [3072][2048] WqT|WkT|WvT, then WoT (reuse)
  bf16* qp  = WT3 + 6291456;      // [4096][2048]
  bf16* kp  = qp + 8388608;       // [4096][512]
  bf16* vT  = kp + 2097152;       // [8][128][2048]
  // total 27.3M bf16 = 54.6 MB

  f2b<<<8192, 256, 0, stream>>>(x, xb, 2097152);
  transpose_w_f2b<<<dim3(32, 32), 256, 0, stream>>>(Wq, WT3, 2048, QSCALE);
  transpose_w_f2b<<<dim3(8, 32), 256, 0, stream>>>(Wk, WT3 + (long)2048 * 2048, 512, 1.0f);
  transpose_w_f2b<<<dim3(8, 32), 256, 0, stream>>>(Wv, WT3 + (long)2560 * 2048, 512, 1.0f);

  gemm_qkv<<<dim3(24, 32), 256, 0, stream>>>(xb, WT3, qp, kp, vT);

  transpose_w_f2b<<<dim3(32, 32), 256, 0, stream>>>(Wo, WT3, 2048, 1.0f);  // reuse

  bf16* ao = xb;  // x dead after QKV gemm
  attn_fwd<<<dim3(16, 16, 2), 512, 0, stream>>>(qp, kp, vT, ao);

  gemm_out<<<dim3(16, 32), 256, 0, stream>>>(ao, WT3, out);
}